// Round 11
// baseline (148.126 us; speedup 1.0000x reference)
//
#include <hip/hip_runtime.h>

typedef __attribute__((ext_vector_type(8))) short short8;
typedef __attribute__((ext_vector_type(4))) float floatx4;
typedef _Float16 half8 __attribute__((ext_vector_type(8)));
typedef _Float16 half4 __attribute__((ext_vector_type(4)));
typedef _Float16 half2v __attribute__((ext_vector_type(2)));

static __device__ __forceinline__ unsigned short f2bf(float x) {
    unsigned int u = __builtin_bit_cast(unsigned int, x);
    unsigned int r = (u + 0x7FFFu + ((u >> 16) & 1u)) >> 16;
    return (unsigned short)r;
}

// ------------------------------------------------------------------
// Phase A1: factorized GEMM (R6/R7/R10-verified math):
//   ud[i] = zd[i] @ W1[0:128]  + 0.5*b1   (10000 x 128, fp16)
//   us[j] = zs[j] @ W1[128:256] + 0.5*b1  (15000 x 128, fp16)
// ------------------------------------------------------------------
static __device__ void phase_gemm(
    int b, const float* __restrict__ zd, const float* __restrict__ zs,
    const float* __restrict__ W1, const float* __restrict__ b1,
    _Float16* __restrict__ ud, _Float16* __restrict__ us,
    int ndrows, int nsrows, int ntd)
{
    const int tid  = threadIdx.x;
    const int lane = tid & 63;
    const int wave = tid >> 6;
    const int wh   = wave >> 1;
    const int we   = wave & 1;
    const int l15  = lane & 15;
    const int quad = lane >> 4;

    const bool isD = (b < ntd);
    const float* __restrict__ z = isD ? zd : zs;
    _Float16* __restrict__ u = isD ? ud : us;
    const int nrows = isD ? ndrows : nsrows;
    const int m0    = (isD ? b : b - ntd) * 64;
    const int koff0 = isD ? 0 : 128;
    const int whbase = wh * 64;

    short8 wfrag[16];
    #pragma unroll
    for (int s = 0; s < 4; ++s)
        #pragma unroll
        for (int mt = 0; mt < 4; ++mt) {
            short8 t;
            #pragma unroll
            for (int j = 0; j < 8; ++j)
                t[j] = (short)f2bf(
                    W1[(size_t)(koff0 + s * 32 + quad * 8 + j) * 128 +
                       whbase + mt * 16 + l15]);
            wfrag[s * 4 + mt] = t;
        }

    floatx4 acc[2][4];
    #pragma unroll
    for (int mt = 0; mt < 4; ++mt) {
        floatx4 bb = *reinterpret_cast<const floatx4*>(&b1[whbase + mt * 16 + quad * 4]);
        bb *= 0.5f;
        acc[0][mt] = bb;
        acc[1][mt] = bb;
    }

    int rowi[2], rowc[2];
    #pragma unroll
    for (int et = 0; et < 2; ++et) {
        rowi[et] = m0 + we * 32 + et * 16 + l15;
        rowc[et] = rowi[et] < nrows ? rowi[et] : nrows - 1;
    }

    #pragma unroll
    for (int s = 0; s < 4; ++s) {
        short8 bf[2];
        #pragma unroll
        for (int et = 0; et < 2; ++et) {
            const float* src = &z[(size_t)rowc[et] * 128 + s * 32 + quad * 8];
            floatx4 lo = *reinterpret_cast<const floatx4*>(src);
            floatx4 hi = *reinterpret_cast<const floatx4*>(src + 4);
            short8 t;
            t[0] = (short)f2bf(lo[0]); t[1] = (short)f2bf(lo[1]);
            t[2] = (short)f2bf(lo[2]); t[3] = (short)f2bf(lo[3]);
            t[4] = (short)f2bf(hi[0]); t[5] = (short)f2bf(hi[1]);
            t[6] = (short)f2bf(hi[2]); t[7] = (short)f2bf(hi[3]);
            bf[et] = t;
        }
        #pragma unroll
        for (int et = 0; et < 2; ++et)
            #pragma unroll
            for (int mt = 0; mt < 4; ++mt)
                acc[et][mt] = __builtin_amdgcn_mfma_f32_16x16x32_bf16(
                    wfrag[s * 4 + mt], bf[et], acc[et][mt], 0, 0, 0);
    }

    #pragma unroll
    for (int et = 0; et < 2; ++et) {
        if (rowi[et] < nrows) {
            #pragma unroll
            for (int mt = 0; mt < 4; ++mt) {
                half4 hv;
                #pragma unroll
                for (int rr = 0; rr < 4; ++rr) hv[rr] = (_Float16)acc[et][mt][rr];
                *reinterpret_cast<half4*>(
                    &u[(size_t)rowi[et] * 128 + whbase + mt * 16 + quad * 4]) = hv;
            }
        }
    }
}

// ------------------------------------------------------------------
// Phase A2: LDS-aggregated histogram over bins = row >> 6 (64 drug rows/bin).
// Rides in k_mid, overlapped with the GEMM blocks.
// ------------------------------------------------------------------
static __device__ void phase_hist(
    int hb, const int* __restrict__ row,
    unsigned* __restrict__ ghist, int nbins)
{
    __shared__ unsigned lh[192];
    const int tid = threadIdx.x;
    for (int i = tid; i < nbins; i += 256) lh[i] = 0;
    __syncthreads();
    const long base = (long)hb * 2048;
    #pragma unroll
    for (int k = 0; k < 8; ++k) {
        int r = row[base + k * 256 + tid];
        atomicAdd(&lh[r >> 6], 1u);
    }
    __syncthreads();
    for (int i = tid; i < nbins; i += 256) {
        unsigned v = lh[i];
        if (v) atomicAdd(&ghist[i], v);
    }
}

__global__ __launch_bounds__(256, 2) void k_mid(
    const float* __restrict__ zd, const float* __restrict__ zs,
    const float* __restrict__ W1, const float* __restrict__ b1,
    _Float16* __restrict__ ud, _Float16* __restrict__ us,
    int ndrows, int nsrows, int ntd, int nbg,
    const int* __restrict__ row,
    unsigned* __restrict__ ghist, int nbins)
{
    const int b = blockIdx.x;
    if (b < nbg) phase_gemm(b, zd, zs, W1, b1, ud, us, ndrows, nsrows, ntd);
    else         phase_hist(b - nbg, row, ghist, nbins);
}

// ------------------------------------------------------------------
// Phase B: counting-sort scatter, NO scan kernel. Each block redundantly
// prefix-sums ghist[157] in LDS (~0.3us), LDS-tickets its 2048 edges, claims
// per-bin ranges via one global atomicAdd per nonzero bin (gcur starts at 0;
// final pos = prefix[bin] + global_ticket + local_rank). Records: u64 =
// row | col<<14 | eid<<32. Bucket-internal order irrelevant (eid carried;
// one writer per out[eid]).
// ------------------------------------------------------------------
__global__ __launch_bounds__(256, 4) void k_scatter(
    const int* __restrict__ row, const int* __restrict__ col,
    const unsigned* __restrict__ ghist, unsigned* __restrict__ gcur,
    unsigned long long* __restrict__ recbuf, int nbins)
{
    __shared__ unsigned pb[192];     // global prefix bases
    __shared__ unsigned lcnt[192];   // local counts -> then local ranks
    __shared__ unsigned gt[192];     // global tickets for this block
    const int tid = threadIdx.x;
    for (int i = tid; i < nbins; i += 256) lcnt[i] = 0;
    __syncthreads();

    const long base = (long)blockIdx.x * 2048;
    unsigned rnk[8], rcv[8];
    int binv[8];
    #pragma unroll
    for (int k = 0; k < 8; ++k) {
        long e = base + k * 256 + tid;    // coalesced
        int r = row[e], c = col[e];
        rcv[k] = (unsigned)r | ((unsigned)c << 14);
        binv[k] = r >> 6;
        rnk[k] = atomicAdd(&lcnt[binv[k]], 1u);
    }
    __syncthreads();
    if (tid == 0) {                        // redundant per-block prefix: ~free
        unsigned run = 0;
        for (int i = 0; i < nbins; ++i) { pb[i] = run; run += ghist[i]; }
    }
    for (int i = tid; i < nbins; i += 256) {
        unsigned cnt = lcnt[i];
        if (cnt) gt[i] = atomicAdd(&gcur[i], cnt);
    }
    __syncthreads();
    #pragma unroll
    for (int k = 0; k < 8; ++k) {
        long e = base + k * 256 + tid;
        unsigned pos = pb[binv[k]] + gt[binv[k]] + rnk[k];
        recbuf[pos] = (unsigned long long)rcv[k] | ((unsigned long long)(unsigned)e << 32);
    }
}

// ------------------------------------------------------------------
// Phase C: edge eval on bin-sorted CONTIGUOUS record ranges.
// Block (bin, worker): stages the bin's 64-row ud slice (16KB) into LDS once
// -> u reads are LDS (conflict-free b128 pattern). v gathered from us (3.84MB,
// L2-resident on every XCD -- R10 FETCH data). 16KB LDS + <=64 VGPR
// (launch_bounds(256,8)) -> 8 blocks/CU = 32 waves/CU of TLP; each worker
// streams one contiguous ~460-edge range with the R7-proven 2-deep pipeline.
// ------------------------------------------------------------------
__global__ __launch_bounds__(256, 8) void k_edge(
    const _Float16* __restrict__ ud, const _Float16* __restrict__ us,
    const unsigned* __restrict__ ghist, const unsigned long long* __restrict__ recbuf,
    const float* __restrict__ w2, const float* __restrict__ b2,
    float* __restrict__ out, int ndrows, int nbins)
{
    __shared__ _Float16 uL[64 * 128];    // 16 KB: 64 rows x 128 fp16
    __shared__ unsigned red[256];
    __shared__ unsigned sh_base, sh_cnt;

    const int tid  = threadIdx.x;
    const int lane = tid & 63;
    const int wave = tid >> 6;
    const int le   = lane >> 3;          // edge slot 0..7
    const int q    = lane & 7;           // 16B sub-chunk 0..7
    const int lslot = wave * 8 + le;     // 0..31 within chunk

    const int G   = (int)gridDim.x;
    const int b   = blockIdx.x;
    const int bin = b % nbins;
    const int w   = b / nbins;
    const int nwq = G / nbins, nwr = G % nbins;
    const int nwb = nwq + (bin < nwr ? 1 : 0);   // workers for this bin

    // ---- parallel prefix: base = sum(ghist[0..bin)), cnt = ghist[bin] ----
    red[tid] = (tid < bin) ? ghist[tid] : 0u;    // nbins <= 256
    __syncthreads();
    for (int off = 128; off > 0; off >>= 1) {
        if (tid < off) red[tid] += red[tid + off];
        __syncthreads();
    }
    if (tid == 0) { sh_base = red[0]; sh_cnt = ghist[bin]; }

    // ---- stage ud slice for this bin (runs before the sync below) ----
    const int r0 = bin << 6;
    int nr = ndrows - r0; if (nr > 64) nr = 64;
    for (int i = tid; i < nr * 16; i += 256) {
        int rr = i >> 4, pp = i & 15;
        *reinterpret_cast<half8*>(&uL[rr * 128 + pp * 8]) =
            *reinterpret_cast<const half8*>(&ud[(size_t)(r0 + rr) * 128 + pp * 8]);
    }

#if __has_builtin(__builtin_amdgcn_fdot2)
    half2v w2h[8];                       // w2[i*64 + q*8 + 2p .. +1]
    #pragma unroll
    for (int i = 0; i < 2; ++i)
        #pragma unroll
        for (int p = 0; p < 4; ++p) {
            half2v t;
            t[0] = (_Float16)w2[i * 64 + q * 8 + 2 * p];
            t[1] = (_Float16)w2[i * 64 + q * 8 + 2 * p + 1];
            w2h[i * 4 + p] = t;
        }
#else
    float w2r[16];
    #pragma unroll
    for (int i = 0; i < 2; ++i) {
        *reinterpret_cast<floatx4*>(&w2r[i * 8]) =
            *reinterpret_cast<const floatx4*>(&w2[i * 64 + q * 8]);
        *reinterpret_cast<floatx4*>(&w2r[i * 8 + 4]) =
            *reinterpret_cast<const floatx4*>(&w2[i * 64 + q * 8 + 4]);
    }
#endif
    const float b2v = b2[0];
    __syncthreads();

    const unsigned base = sh_base;
    const unsigned cnt  = sh_cnt;
    const unsigned K  = (cnt + (unsigned)nwb - 1u) / (unsigned)nwb;
    unsigned s0 = (unsigned)w * K;
    if (s0 >= cnt) return;
    unsigned s1 = s0 + K; if (s1 > cnt) s1 = cnt;
    const int tend = (int)((s1 - s0 + 31u) >> 5);   // chunks of 32

#define LOADREC(RV, VV, tt)                                                    \
    {                                                                          \
        unsigned li = s0 + (unsigned)(tt) * 32u + (unsigned)lslot;             \
        VV = li < s1;                                                          \
        RV = recbuf[base + (VV ? li : s0)];                                    \
    }

#define GATHER(D, RV)                                                          \
    {                                                                          \
        unsigned c = ((unsigned)(RV) >> 14) & 16383u;                          \
        const _Float16* vp = us + (size_t)c * 128 + q * 8;                     \
        D[0] = *reinterpret_cast<const half8*>(vp);                            \
        D[1] = *reinterpret_cast<const half8*>(vp + 64);                       \
    }

#if __has_builtin(__builtin_amdgcn_fdot2)
#define DOTBODY(D, RV, accv)                                                   \
    const unsigned rl = ((unsigned)(RV) & 16383u) - (unsigned)r0;              \
    const _Float16* up = &uL[rl * 128 + q * 8];                                \
    half8 s0v = *reinterpret_cast<const half8*>(up) + D[0];                    \
    s0v = __builtin_elementwise_max(s0v, (half8)(_Float16)0.f);                \
    half8 s1v = *reinterpret_cast<const half8*>(up + 64) + D[1];               \
    s1v = __builtin_elementwise_max(s1v, (half8)(_Float16)0.f);                \
    _Pragma("unroll")                                                          \
    for (int p = 0; p < 4; ++p) {                                              \
        half2v pr0; pr0[0] = s0v[2 * p]; pr0[1] = s0v[2 * p + 1];              \
        accv = __builtin_amdgcn_fdot2(pr0, w2h[p], accv, false);               \
        half2v pr1; pr1[0] = s1v[2 * p]; pr1[1] = s1v[2 * p + 1];              \
        accv = __builtin_amdgcn_fdot2(pr1, w2h[4 + p], accv, false);           \
    }
#else
#define DOTBODY(D, RV, accv)                                                   \
    const unsigned rl = ((unsigned)(RV) & 16383u) - (unsigned)r0;              \
    const _Float16* up = &uL[rl * 128 + q * 8];                                \
    half8 s0v = *reinterpret_cast<const half8*>(up) + D[0];                    \
    s0v = __builtin_elementwise_max(s0v, (half8)(_Float16)0.f);                \
    half8 s1v = *reinterpret_cast<const half8*>(up + 64) + D[1];               \
    s1v = __builtin_elementwise_max(s1v, (half8)(_Float16)0.f);                \
    _Pragma("unroll")                                                          \
    for (int j = 0; j < 8; ++j) {                                              \
        accv += (float)s0v[j] * w2r[j];                                        \
        accv += (float)s1v[j] * w2r[8 + j];                                    \
    }
#endif

#define COMPUTE(D, RV, VV)                                                     \
    {                                                                          \
        float acc = 0.f;                                                       \
        DOTBODY(D, RV, acc)                                                    \
        acc += __shfl_xor(acc, 1);                                             \
        acc += __shfl_xor(acc, 2);                                             \
        acc += __shfl_xor(acc, 4);                                             \
        if ((VV) && q == 0) out[(unsigned)((RV) >> 32)] = acc + b2v;           \
    }

    unsigned long long recA, recB = 0, recA2 = 0, recB2 = 0;
    bool vA, vB = false, vA2 = false, vB2 = false;
    int t = 0;
    LOADREC(recA, vA, 0)
    bool hasB = (1 < tend);
    if (hasB) LOADREC(recB, vB, 1)

    half8 dA[2], dB[2];
    while (true) {
        // v-gathers for both chunks first (L2-resident; back-to-back issue)
        GATHER(dA, recA)
        if (hasB) GATHER(dB, recB)

        // records for the NEXT pair — a full iteration of slack
        bool hasA2 = (t + 2 < tend), hasB2 = (t + 3 < tend);
        if (hasA2) LOADREC(recA2, vA2, t + 2)
        if (hasB2) LOADREC(recB2, vB2, t + 3)

        COMPUTE(dA, recA, vA)
        if (!hasB) break;
        COMPUTE(dB, recB, vB)

        if (!hasA2) break;
        recA = recA2; vA = vA2;
        recB = recB2; vB = vB2;
        hasB = hasB2;
        t += 2;
    }
#undef LOADREC
#undef GATHER
#undef DOTBODY
#undef COMPUTE
}

extern "C" void kernel_launch(void* const* d_in, const int* in_sizes, int n_in,
                              void* d_out, int out_size, void* d_ws, size_t ws_size,
                              hipStream_t stream) {
    const float* zd = (const float*)d_in[0];
    const float* zs = (const float*)d_in[1];
    const int*   row = (const int*)d_in[2];
    const int*   col = (const int*)d_in[3];
    const float* W1 = (const float*)d_in[4];
    const float* b1 = (const float*)d_in[5];
    const float* w2 = (const float*)d_in[6];
    const float* b2 = (const float*)d_in[7];
    float* out = (float*)d_out;

    const int nd = in_sizes[0];   // 10000*128
    const int ns = in_sizes[1];   // 15000*128
    const int E  = in_sizes[2];   // 1048576 (multiple of 2048)
    const int ndrows = nd / 128;
    const int nsrows = ns / 128;

    const int nbins = (ndrows + 63) >> 6;     // 157 bins of 64 drug rows

    // ws: ud fp16 | us fp16 | ghist u32[192] | gcur u32[192] | recbuf u64[E]
    _Float16* ud = (_Float16*)d_ws;
    _Float16* us = ud + (size_t)ndrows * 128;
    size_t off = (size_t)((char*)(us + (size_t)nsrows * 128) - (char*)d_ws);
    off = (off + 63) & ~(size_t)63;
    unsigned* ghist = (unsigned*)((char*)d_ws + off);
    unsigned* gcur  = ghist + 192;
    unsigned long long* recbuf = (unsigned long long*)
        (((uintptr_t)(gcur + 192) + 63) & ~(uintptr_t)63);

    hipMemsetAsync(ghist, 0, 384 * sizeof(unsigned), stream);

    const int ntd = (ndrows + 63) / 64;   // 157
    const int nts = (nsrows + 63) / 64;   // 235
    const int nbg = ntd + nts;            // 392 GEMM blocks + 512 hist blocks
    hipLaunchKernelGGL(k_mid, dim3(nbg + E / 2048), dim3(256), 0, stream,
                       zd, zs, W1, b1, ud, us, ndrows, nsrows, ntd, nbg,
                       row, ghist, nbins);

    hipLaunchKernelGGL(k_scatter, dim3(E / 2048), dim3(256), 0, stream,
                       row, col, ghist, gcur, recbuf, nbins);

    // 2048 = 8 blocks/CU exactly co-resident (16KB LDS, <=64 VGPR)
    hipLaunchKernelGGL(k_edge, dim3(2048), dim3(256), 0, stream,
                       ud, us, ghist, recbuf, w2, b2, out, ndrows, nbins);
}

// Round 12
// 123.424 us; speedup vs baseline: 1.2001x; 1.2001x over previous
//
#include <hip/hip_runtime.h>

typedef __attribute__((ext_vector_type(8))) short short8;
typedef __attribute__((ext_vector_type(4))) float floatx4;
typedef _Float16 half8 __attribute__((ext_vector_type(8)));
typedef _Float16 half4 __attribute__((ext_vector_type(4)));
typedef _Float16 half2v __attribute__((ext_vector_type(2)));

static __device__ __forceinline__ unsigned short f2bf(float x) {
    unsigned int u = __builtin_bit_cast(unsigned int, x);
    unsigned int r = (u + 0x7FFFu + ((u >> 16) & 1u)) >> 16;
    return (unsigned short)r;
}

// Merged mid phase (R6 champion structure). Blocks [0, nbg): factorized GEMM,
// W1 fragments gathered directly from W1 (128 KB, L2-hot):
//   ud[i] = zd[i] @ W1[0:128]  + 0.5*b1   (10000 x 128, fp16)
//   us[j] = zs[j] @ W1[128:256] + 0.5*b1  (15000 x 128, fp16)
// Blocks [nbg, nbg+E/2048): class-scatter. Class = (row>=rowh)*2 | (col>=colh).
// Each class's gather footprint (~1.28MB ud-half + ~1.92MB us-half = 3.2MB) fits
// one XCD's 4MiB L2. Records fused u64: low = row | col<<14, high = edge id.
// Ballot-aggregated compaction, 4 global atomicAdds per block; bucket-internal
// order irrelevant (eid carried; out[eid] has exactly one writer).
__global__ __launch_bounds__(256, 2) void mid_kernel(
    const float* __restrict__ zd, const float* __restrict__ zs,
    const float* __restrict__ W1, const float* __restrict__ b1,
    _Float16* __restrict__ ud, _Float16* __restrict__ us,
    int ndrows, int nsrows, int ntd, int nbg,
    const int* __restrict__ row, const int* __restrict__ col,
    unsigned* __restrict__ gcur, unsigned long long* __restrict__ recbuf,
    int E, int rowh, int colh)
{
    if ((int)blockIdx.x < nbg) {
        // ---------------- factor GEMM ----------------
        const int tid  = threadIdx.x;
        const int lane = tid & 63;
        const int wave = tid >> 6;
        const int wh   = wave >> 1;
        const int we   = wave & 1;
        const int l15  = lane & 15;
        const int quad = lane >> 4;

        const int b = blockIdx.x;
        const bool isD = (b < ntd);
        const float* __restrict__ z = isD ? zd : zs;
        _Float16* __restrict__ u = isD ? ud : us;
        const int nrows = isD ? ndrows : nsrows;
        const int m0    = (isD ? b : b - ntd) * 64;
        const int koff0 = isD ? 0 : 128;
        const int whbase = wh * 64;

        short8 wfrag[16];
        #pragma unroll
        for (int s = 0; s < 4; ++s)
            #pragma unroll
            for (int mt = 0; mt < 4; ++mt) {
                short8 t;
                #pragma unroll
                for (int j = 0; j < 8; ++j)
                    t[j] = (short)f2bf(
                        W1[(size_t)(koff0 + s * 32 + quad * 8 + j) * 128 +
                           whbase + mt * 16 + l15]);
                wfrag[s * 4 + mt] = t;
            }

        floatx4 acc[2][4];
        #pragma unroll
        for (int mt = 0; mt < 4; ++mt) {
            floatx4 bb = *reinterpret_cast<const floatx4*>(&b1[whbase + mt * 16 + quad * 4]);
            bb *= 0.5f;                   // each half contributes b1/2 -> sum = b1
            acc[0][mt] = bb;
            acc[1][mt] = bb;
        }

        int rowi[2], rowc[2];
        #pragma unroll
        for (int et = 0; et < 2; ++et) {
            rowi[et] = m0 + we * 32 + et * 16 + l15;
            rowc[et] = rowi[et] < nrows ? rowi[et] : nrows - 1;
        }

        #pragma unroll
        for (int s = 0; s < 4; ++s) {
            short8 bf[2];
            #pragma unroll
            for (int et = 0; et < 2; ++et) {
                const float* src = &z[(size_t)rowc[et] * 128 + s * 32 + quad * 8];
                floatx4 lo = *reinterpret_cast<const floatx4*>(src);
                floatx4 hi = *reinterpret_cast<const floatx4*>(src + 4);
                short8 t;
                t[0] = (short)f2bf(lo[0]); t[1] = (short)f2bf(lo[1]);
                t[2] = (short)f2bf(lo[2]); t[3] = (short)f2bf(lo[3]);
                t[4] = (short)f2bf(hi[0]); t[5] = (short)f2bf(hi[1]);
                t[6] = (short)f2bf(hi[2]); t[7] = (short)f2bf(hi[3]);
                bf[et] = t;
            }
            #pragma unroll
            for (int et = 0; et < 2; ++et)
                #pragma unroll
                for (int mt = 0; mt < 4; ++mt)
                    acc[et][mt] = __builtin_amdgcn_mfma_f32_16x16x32_bf16(
                        wfrag[s * 4 + mt], bf[et], acc[et][mt], 0, 0, 0);
        }

        #pragma unroll
        for (int et = 0; et < 2; ++et) {
            if (rowi[et] < nrows) {
                #pragma unroll
                for (int mt = 0; mt < 4; ++mt) {
                    half4 hv;
                    #pragma unroll
                    for (int rr = 0; rr < 4; ++rr) hv[rr] = (_Float16)acc[et][mt][rr];
                    *reinterpret_cast<half4*>(
                        &u[(size_t)rowi[et] * 128 + whbase + mt * 16 + quad * 4]) = hv;
                }
            }
        }
    } else {
        // ---------------- class scatter ----------------
        __shared__ unsigned wl[4][4];    // [wave][class]
        __shared__ unsigned gb[4];       // block base per class
        const int tid  = threadIdx.x;
        const int lane = tid & 63;
        const int wave = tid >> 6;
        const int sb   = blockIdx.x - nbg;
        const long base = (long)sb * 2048;    // E % 2048 == 0

        unsigned rc[8], off[8];
        int cls0, cls1, cls2, cls3, cls4, cls5, cls6, cls7;
        unsigned w0 = 0, w1 = 0, w2c = 0, w3 = 0;   // per-wave running class counts

        #pragma unroll
        for (int k = 0; k < 8; ++k) {
            long e = base + k * 256 + tid;   // coalesced per wave
            int r = row[e], c = col[e];
            rc[k] = (unsigned)r | ((unsigned)c << 14);
            int cl = ((r >= rowh) ? 2 : 0) | ((c >= colh) ? 1 : 0);
            unsigned long long m0 = __ballot(cl == 0);
            unsigned long long m1 = __ballot(cl == 1);
            unsigned long long m2 = __ballot(cl == 2);
            unsigned long long m3 = __ballot(cl == 3);
            unsigned long long mlt = (1ull << lane) - 1ull;
            unsigned long long mc = (cl == 0) ? m0 : (cl == 1) ? m1 : (cl == 2) ? m2 : m3;
            unsigned wb = (cl == 0) ? w0 : (cl == 1) ? w1 : (cl == 2) ? w2c : w3;
            off[k] = wb + (unsigned)__popcll(mc & mlt);
            w0 += (unsigned)__popcll(m0); w1 += (unsigned)__popcll(m1);
            w2c += (unsigned)__popcll(m2); w3 += (unsigned)__popcll(m3);
            switch (k) {   // static stores of cls (avoid runtime-indexed reg array)
                case 0: cls0 = cl; break; case 1: cls1 = cl; break;
                case 2: cls2 = cl; break; case 3: cls3 = cl; break;
                case 4: cls4 = cl; break; case 5: cls5 = cl; break;
                case 6: cls6 = cl; break; default: cls7 = cl; break;
            }
        }
        if (lane < 4) {
            unsigned wv = (lane == 0) ? w0 : (lane == 1) ? w1 : (lane == 2) ? w2c : w3;
            wl[wave][lane] = wv;
        }
        __syncthreads();
        if (tid < 4) {
            unsigned tot = wl[0][tid] + wl[1][tid] + wl[2][tid] + wl[3][tid];
            gb[tid] = atomicAdd(&gcur[tid], tot);
        }
        __syncthreads();
        unsigned p0 = 0, p1 = 0, p2 = 0, p3 = 0;   // prefix of earlier waves
        for (int w = 0; w < 4; ++w)
            if (w < wave) { p0 += wl[w][0]; p1 += wl[w][1]; p2 += wl[w][2]; p3 += wl[w][3]; }

        #pragma unroll
        for (int k = 0; k < 8; ++k) {
            long e = base + k * 256 + tid;
            int cl = (k == 0) ? cls0 : (k == 1) ? cls1 : (k == 2) ? cls2 : (k == 3) ? cls3
                   : (k == 4) ? cls4 : (k == 5) ? cls5 : (k == 6) ? cls6 : cls7;
            unsigned pre = (cl == 0) ? p0 : (cl == 1) ? p1 : (cl == 2) ? p2 : p3;
            unsigned pos = gb[cl] + pre + off[k];
            recbuf[(size_t)cl * E + pos] =
                (unsigned long long)rc[k] | ((unsigned long long)(unsigned)e << 32);
        }
    }
}

// Edge phase (R6 champion): class-partitioned gather. Block b -> XCD b&7
// (round-robin heuristic), class = (b&7)>>1, so each XCD pair's L2 only sees its
// class's 3.2MB ud/us slice -> gathers are L2-hits. 8 lanes/edge, coalesced 16B
// loads (2 full lines per instr per table), 1-ahead u64-record prefetch, strided
// chunks. lb(256,8), low VGPR -> 8 blocks/CU, 32 waves/CU of TLP.
__global__ __launch_bounds__(256, 8) void edge_eval(
    const _Float16* __restrict__ ud, const _Float16* __restrict__ us,
    const unsigned* __restrict__ gcur, const unsigned long long* __restrict__ recbuf,
    const float* __restrict__ w2, const float* __restrict__ b2,
    float* __restrict__ out, int E)
{
    const int tid  = threadIdx.x;
    const int lane = tid & 63;
    const int wave = tid >> 6;
    const int le   = lane >> 3;          // edge slot 0..7
    const int q    = lane & 7;           // 16B sub-chunk 0..7
    const int lslot = wave * 8 + le;     // 0..31 within chunk

    const int b    = blockIdx.x;
    const int xcd  = b & 7;
    const int cls  = xcd >> 1;
    const int sub  = ((b >> 3) << 1) | (xcd & 1);
    const int NSUB = (int)((gridDim.x >> 3) << 1);

    const unsigned n = gcur[cls];
    const int nch = (int)((n + 31u) >> 5);
    const unsigned long long* __restrict__ recb = recbuf + (size_t)cls * E;

#if __has_builtin(__builtin_amdgcn_fdot2)
    half2v w2h[8];                       // w2[i*64 + q*8 + 2p .. +1]
    #pragma unroll
    for (int i = 0; i < 2; ++i)
        #pragma unroll
        for (int p = 0; p < 4; ++p) {
            half2v t;
            t[0] = (_Float16)w2[i * 64 + q * 8 + 2 * p];
            t[1] = (_Float16)w2[i * 64 + q * 8 + 2 * p + 1];
            w2h[i * 4 + p] = t;
        }
#else
    float w2r[16];
    #pragma unroll
    for (int i = 0; i < 2; ++i) {
        *reinterpret_cast<floatx4*>(&w2r[i * 8]) =
            *reinterpret_cast<const floatx4*>(&w2[i * 64 + q * 8]);
        *reinterpret_cast<floatx4*>(&w2r[i * 8 + 4]) =
            *reinterpret_cast<const floatx4*>(&w2[i * 64 + q * 8 + 4]);
    }
#endif
    const float b2v = b2[0];

    int t = sub;
    if (t >= nch) return;

    unsigned ei0 = (unsigned)t * 32u + (unsigned)lslot;
    bool v0 = ei0 < n;
    unsigned long long rec0 = recb[v0 ? ei0 : 0u];

    while (true) {
        const int tn = t + NSUB;

        // gathers for current chunk (L2-resident class slice)
        unsigned r = (unsigned)rec0 & 16383u;
        unsigned c = ((unsigned)rec0 >> 14) & 16383u;
        const _Float16* up = ud + (size_t)r * 128 + q * 8;
        const _Float16* vp = us + (size_t)c * 128 + q * 8;
        half8 U0 = *reinterpret_cast<const half8*>(up);
        half8 U1 = *reinterpret_cast<const half8*>(up + 64);
        half8 V0 = *reinterpret_cast<const half8*>(vp);
        half8 V1 = *reinterpret_cast<const half8*>(vp + 64);

        // prefetch next chunk's fused record
        unsigned long long rec1 = 0;
        bool v1 = false;
        if (tn < nch) {
            unsigned ei1 = (unsigned)tn * 32u + (unsigned)lslot;
            v1 = ei1 < n;
            rec1 = recb[v1 ? ei1 : 0u];
        }

        // compute: relu(u+v) . w2  (fp16 packed add/max, f32 accumulate)
        float acc = 0.f;
        half8 s0 = U0 + V0;
        s0 = __builtin_elementwise_max(s0, (half8)(_Float16)0.f);
        half8 s1 = U1 + V1;
        s1 = __builtin_elementwise_max(s1, (half8)(_Float16)0.f);
#if __has_builtin(__builtin_amdgcn_fdot2)
        #pragma unroll
        for (int p = 0; p < 4; ++p) {
            half2v pr0; pr0[0] = s0[2 * p]; pr0[1] = s0[2 * p + 1];
            acc = __builtin_amdgcn_fdot2(pr0, w2h[p], acc, false);
            half2v pr1; pr1[0] = s1[2 * p]; pr1[1] = s1[2 * p + 1];
            acc = __builtin_amdgcn_fdot2(pr1, w2h[4 + p], acc, false);
        }
#else
        #pragma unroll
        for (int j = 0; j < 8; ++j) {
            acc += (float)s0[j] * w2r[j];
            acc += (float)s1[j] * w2r[8 + j];
        }
#endif
        acc += __shfl_xor(acc, 1);
        acc += __shfl_xor(acc, 2);
        acc += __shfl_xor(acc, 4);
        if (v0 && q == 0) out[(unsigned)(rec0 >> 32)] = acc + b2v;

        if (tn >= nch) break;
        t = tn; rec0 = rec1; v0 = v1;
    }
}

extern "C" void kernel_launch(void* const* d_in, const int* in_sizes, int n_in,
                              void* d_out, int out_size, void* d_ws, size_t ws_size,
                              hipStream_t stream) {
    const float* zd = (const float*)d_in[0];
    const float* zs = (const float*)d_in[1];
    const int*   row = (const int*)d_in[2];
    const int*   col = (const int*)d_in[3];
    const float* W1 = (const float*)d_in[4];
    const float* b1 = (const float*)d_in[5];
    const float* w2 = (const float*)d_in[6];
    const float* b2 = (const float*)d_in[7];
    float* out = (float*)d_out;

    const int nd = in_sizes[0];   // 10000*128
    const int ns = in_sizes[1];   // 15000*128
    const int E  = in_sizes[2];   // 1048576 (multiple of 2048)
    const int ndrows = nd / 128;
    const int nsrows = ns / 128;
    const int rowh = ndrows >> 1;  // 5000
    const int colh = nsrows >> 1;  // 7500

    // ws: ud fp16 | us fp16 | gcur (64B) | recbuf u64 4*E (~32MB)
    _Float16* ud = (_Float16*)d_ws;
    _Float16* us = ud + (size_t)ndrows * 128;
    size_t off = (size_t)((char*)(us + (size_t)nsrows * 128) - (char*)d_ws);
    off = (off + 63) & ~(size_t)63;
    unsigned* gcur = (unsigned*)((char*)d_ws + off);
    unsigned long long* recbuf = (unsigned long long*)((char*)gcur + 64);

    hipMemsetAsync(gcur, 0, 16 * sizeof(unsigned), stream);

    const int ntd = (ndrows + 63) / 64;   // 157
    const int nts = (nsrows + 63) / 64;   // 235
    const int nbg = ntd + nts;            // 392 GEMM blocks
    const int nsb = E / 2048;             // 512 scatter blocks
    hipLaunchKernelGGL(mid_kernel, dim3(nbg + nsb), dim3(256), 0, stream,
                       zd, zs, W1, b1, ud, us, ndrows, nsrows, ntd, nbg,
                       row, col, gcur, recbuf, E, rowh, colh);

    hipLaunchKernelGGL(edge_eval, dim3(2048), dim3(256), 0, stream,
                       ud, us, gcur, recbuf, w2, b2, out, E);
}